// Round 1
// 133.569 us; speedup vs baseline: 1.2342x; 1.2342x over previous
//
#include <hip/hip_runtime.h>
#include <float.h>
#include <math.h>

// NPairLoss MI355X r8.
// prep (+class-list build) -> rowsel (wave-parallel gumbel argmax) ->
// fused (16-row/wave A-resident MFMA, per-kc ping-pong staged B, exp2-domain online lse,
// 4 blocks/CU) -> finale (log2-domain merge, ln2 conversion).

#define B_N 8192
#define D_K 256
#define NCLS 100
#define MAXC 512
#define NSPLIT 16
#define NPART NSPLIT
#define JR (B_N / NSPLIT)      // 512
#define BI 64
#define BJ 128
#define NJT (JR / BJ)          // 4
#define BK 64
#define NKC (D_K / BK)         // 4
#define NEG_INF -1e30f
#define C2F  (-14.426950408889634f)   // -10/T' * log2(e)  (T=0.1)
#define K2A  (28.853900817779268f)    // +20 * log2(e)
#define LN2F (0.6931471805599453f)

typedef __attribute__((ext_vector_type(8))) short bf16x8;
typedef __attribute__((ext_vector_type(4))) float f32x4;
typedef unsigned short ushort_t;

__device__ __forceinline__ float ex2(float x){ return __builtin_amdgcn_exp2f(x); }
__device__ __forceinline__ float lg2(float x){ return __builtin_amdgcn_logf(x); }

// ---------------- threefry2x32 / jax gumbel (bit-exact, known-good) ----------------
__device__ __forceinline__ unsigned rotl32(unsigned x, int d){ return (x << d) | (x >> (32 - d)); }

__device__ __forceinline__ float gumbel_at(unsigned idx){
  const unsigned HALF = (unsigned)B_N * (unsigned)B_N / 2u;
  unsigned c0, c1; bool second;
  if (idx < HALF){ c0 = idx; c1 = idx + HALF; second = false; }
  else            { c0 = idx - HALF; c1 = idx; second = true; }
  const unsigned ks0 = 0u, ks1 = 42u, ks2 = 0u ^ 42u ^ 0x1BD11BDAu;
  unsigned x0 = c0 + ks0, x1 = c1 + ks1;
#define TF_RND(r) { x0 += x1; x1 = rotl32(x1, (r)); x1 ^= x0; }
  TF_RND(13) TF_RND(15) TF_RND(26) TF_RND(6)   x0 += ks1; x1 += ks2 + 1u;
  TF_RND(17) TF_RND(29) TF_RND(16) TF_RND(24)  x0 += ks2; x1 += ks0 + 2u;
  TF_RND(13) TF_RND(15) TF_RND(26) TF_RND(6)   x0 += ks0; x1 += ks1 + 3u;
  TF_RND(17) TF_RND(29) TF_RND(16) TF_RND(24)  x0 += ks1; x1 += ks2 + 4u;
  TF_RND(13) TF_RND(15) TF_RND(26) TF_RND(6)   x0 += ks2; x1 += ks0 + 5u;
#undef TF_RND
  unsigned bits = second ? x1 : x0;
  float u = __uint_as_float((bits >> 9) | 0x3f800000u) - 1.0f;
  const float TINY = 1.17549435e-38f;
  u = u * (1.0f - TINY) + TINY;
  u = fmaxf(TINY, u);
  return -logf(-logf(u));
}

__device__ __forceinline__ ushort_t f2bf(float x){
  unsigned u = __float_as_uint(x);
  return (ushort_t)((u + 0x7FFFu + ((u >> 16) & 1u)) >> 16); // RNE
}

__device__ __forceinline__ void async16(const ushort_t* g, ushort_t* lds_wave_base){
  __builtin_amdgcn_global_load_lds((const __attribute__((address_space(1))) void*)g,
                                   (__attribute__((address_space(3))) void*)lds_wave_base,
                                   16, 0, 0);
}

// ---------------- node 1. prep: bf16 convert + sq; tail blocks build class lists ----------------
__global__ __launch_bounds__(256)
void prep_kernel(const float* __restrict__ E, ushort_t* __restrict__ Ebf,
                 float* __restrict__ sq, float* __restrict__ acc4,
                 const int* __restrict__ labels, int* __restrict__ cls_cnt,
                 int* __restrict__ clist){
  __shared__ int s_list[MAXC];
  __shared__ int s_n;
  if (blockIdx.x < B_N / 4){
    if (blockIdx.x == 0 && threadIdx.x < 4) acc4[threadIdx.x] = 0.f;
    int w = threadIdx.x >> 6, lane = threadIdx.x & 63;
    int row = blockIdx.x * 4 + w;
    const float4 v = *reinterpret_cast<const float4*>(E + (size_t)row * D_K + lane * 4);
    float s = v.x*v.x + v.y*v.y + v.z*v.z + v.w*v.w;
#pragma unroll
    for (int off = 32; off > 0; off >>= 1) s += __shfl_down(s, off);
    if (lane == 0) sq[row] = s;
    ushort4 o; o.x = f2bf(v.x); o.y = f2bf(v.y); o.z = f2bf(v.z); o.w = f2bf(v.w);
    *reinterpret_cast<ushort4*>(Ebf + (size_t)row * D_K + lane * 4) = o;
  } else {
    const int c = blockIdx.x - B_N / 4;
    const int tid = threadIdx.x;
    if (tid == 0) s_n = 0;
    __syncthreads();
    for (int t = tid; t < B_N; t += 256){
      if (labels[t] == c){
        int p = atomicAdd(&s_n, 1);
        if (p < MAXC) s_list[p] = t;
      }
    }
    __syncthreads();
    const int n = min(s_n, MAXC);
    if (tid == 0) cls_cnt[c] = n;
    for (int t = tid; t < n; t += 256) clist[c * MAXC + t] = s_list[t];
  }
}

// ---------------- node 2. rowsel: one WAVE per row, lane-parallel gumbel argmax ----------------
__global__ __launch_bounds__(256)
void rowsel_kernel(const int* __restrict__ labels, const int* __restrict__ cls_cnt,
                   const int* __restrict__ clist, int* __restrict__ jsel){
  const int w = threadIdx.x >> 6, lane = threadIdx.x & 63;
  const int row = blockIdx.x * 4 + w;
  const int c = labels[row];
  const int n = min(cls_cnt[c], MAXC);
  float gb = -FLT_MAX; int jb = -1;
  for (int t = lane; t < n; t += 64){
    int j = clist[c * MAXC + t];
    if (j != row){
      float g = gumbel_at(((unsigned)row << 13) + (unsigned)j);
      if (g > gb || (g == gb && (unsigned)j < (unsigned)jb)){ gb = g; jb = j; }
    }
  }
#pragma unroll
  for (int off = 32; off > 0; off >>= 1){
    float g2 = __shfl_down(gb, off);
    int   j2 = __shfl_down(jb, off);
    if (g2 > gb || (g2 == gb && (unsigned)j2 < (unsigned)jb)){ gb = g2; jb = j2; }
  }
  if (lane == 0) jsel[row] = jb;
}

// ---------------- node 3. fused: ping-pong staged MFMA gram + exp2-domain online lse ----------------
__global__ __launch_bounds__(256, 4)
void fused_kernel(const ushort_t* __restrict__ Ebf, const int* __restrict__ labels,
                  const float* __restrict__ sq, const int* __restrict__ jsel,
                  float* __restrict__ numer,
                  float* __restrict__ wsM, float* __restrict__ wsS)
{
  __shared__ __align__(16) ushort_t Bs[2][BJ * BK];  // 2 x 16 KB ping-pong, XOR-swizzled 16B groups
  __shared__ float s_h2j[JR];   // 2 KB  (= C2F * sq[j])
  __shared__ int   s_lj[JR];    // 2 KB
  __shared__ float s_h2i[BI];
  __shared__ int   s_li[BI];
  __shared__ int   s_ji[BI];

  const int bi    = blockIdx.x >> 4;         // 0..127
  const int split = blockIdx.x & 15;         // 0..15
  const int i0    = bi * BI;
  const int jbase = split * JR;
  const int tid   = threadIdx.x;
  const int lane  = tid & 63;
  const int w     = tid >> 6;                // wave 0..3, owns rows [w*16, w*16+16)
  const int quad  = lane >> 4;
  const int l15   = lane & 15;

  for (int t = tid; t < JR; t += 256){ s_h2j[t] = C2F * sq[jbase + t]; s_lj[t] = labels[jbase + t]; }
  if (tid < BI){ s_h2i[tid] = C2F * sq[i0 + tid]; s_li[tid] = labels[i0 + tid]; s_ji[tid] = jsel[i0 + tid]; }

  // A fragments: wave's 16 rows x K=256, register-resident (32 regs)
  bf16x8 af[8];
  {
    const ushort_t* rp = Ebf + (size_t)(i0 + w * 16 + l15) * D_K + quad * 8;
#pragma unroll
    for (int c = 0; c < 8; c++)
      af[c] = *reinterpret_cast<const bf16x8*>(rp + c * 32);
  }

  f32x4 acc[8];
#pragma unroll
  for (int nt = 0; nt < 8; nt++) acc[nt] = (f32x4)0.f;
  float sm[4], ssum[4];
#pragma unroll
  for (int r = 0; r < 4; r++){ sm[r] = NEG_INF; ssum[r] = 0.f; }

  // per-thread staging source offsets: slot = rd*256 + tid -> row r, pre-swizzled group
  int soff[4];
#pragma unroll
  for (int rd = 0; rd < 4; rd++){
    int slot = rd * 256 + tid;
    int r = slot >> 3, gs = slot & 7;
    soff[rd] = r * D_K + ((gs ^ (r & 7)) << 3);
  }

  // prologue: stage (jt=0,kc=0) into Bs[0]
#pragma unroll
  for (int rd = 0; rd < 4; rd++)
    async16(Ebf + (size_t)jbase * D_K + soff[rd],
            &Bs[0][(size_t)(rd * 256 + w * 64) * 8]);
  __syncthreads();  // drains prologue stage + publishes s_*

#pragma unroll 1
  for (int jt = 0; jt < NJT; jt++){
    const int j0 = jbase + jt * BJ;
#pragma unroll
    for (int kc = 0; kc < NKC; kc++){
      const int b = kc & 1;                  // NKC even -> parity restarts at 0 each jt
      // issue next step's stage into the other buffer (covered by this step's MFMA)
      const int sn = jt * NKC + kc + 1;
      if (sn < NJT * NKC){
        const int kcn = sn & 3;
        const size_t gb0 = (size_t)(jbase + (sn >> 2) * BJ) * D_K + (size_t)kcn * BK;
#pragma unroll
        for (int rd = 0; rd < 4; rd++)
          async16(Ebf + gb0 + soff[rd],
                  &Bs[b ^ 1][(size_t)(rd * 256 + w * 64) * 8]);
      }
      // compute current step from Bs[b]
#pragma unroll
      for (int s = 0; s < 2; s++){
        const int g = s * 4 + quad;          // k-group within 64-chunk
        const int c = kc * 2 + s;            // A-fragment chunk index
#pragma unroll
        for (int h = 0; h < 2; h++){         // nt in halves of 4 (caps live bfr at 16 regs)
          bf16x8 bfr[4];
#pragma unroll
          for (int q = 0; q < 4; q++){
            int r = (h * 4 + q) * 16 + l15;
            bfr[q] = *reinterpret_cast<const bf16x8*>(&Bs[b][r * BK + ((g ^ (r & 7)) << 3)]);
          }
#pragma unroll
          for (int q = 0; q < 4; q++)
            acc[h * 4 + q] = __builtin_amdgcn_mfma_f32_16x16x32_bf16(af[c], bfr[q], acc[h * 4 + q], 0, 0, 0);
        }
      }
      if (kc == NKC - 1){
        // ---- epilogue for this 128-col tile (log2-domain) ----
        float h2j[8]; int lj[8];
#pragma unroll
        for (int nt = 0; nt < 8; nt++){
          int ccol = jt * BJ + nt * 16 + l15;
          h2j[nt] = s_h2j[ccol]; lj[nt] = s_lj[ccol];
        }
#pragma unroll
        for (int rr = 0; rr < 4; rr++){
          const int rl = w * 16 + quad * 4 + rr;   // C/D: row = quad*4+reg, col = l15
          const float h2i = s_h2i[rl];
          const int lrow = s_li[rl], jsl = s_ji[rl];
          float sv[8];
#pragma unroll
          for (int nt = 0; nt < 8; nt++){
            float a = acc[nt][rr];
            // sim2 = log2e * sim = min(C2F*(sqi+sqj) + 2*10*log2e*a, 0)
            float sim2 = fminf(fmaf(K2A, a, h2i + h2j[nt]), 0.f);
            int colg = j0 + nt * 16 + l15;
            if (colg == jsl) numer[i0 + rl] = sim2;      // rare predicated store
            sv[nt] = (lj[nt] != lrow) ? sim2 : NEG_INF;  // masks positives + same-label + diag
          }
          float m8 = fmaxf(fmaxf(fmaxf(sv[0],sv[1]),fmaxf(sv[2],sv[3])),
                           fmaxf(fmaxf(sv[4],sv[5]),fmaxf(sv[6],sv[7])));
          float s8 = ex2(sv[0]-m8)+ex2(sv[1]-m8)+ex2(sv[2]-m8)+ex2(sv[3]-m8)
                   + ex2(sv[4]-m8)+ex2(sv[5]-m8)+ex2(sv[6]-m8)+ex2(sv[7]-m8);
          float M = fmaxf(sm[rr], m8);
          ssum[rr] = ssum[rr]*ex2(sm[rr]-M) + s8*ex2(m8-M);
          sm[rr] = M;
        }
#pragma unroll
        for (int nt = 0; nt < 8; nt++) acc[nt] = (f32x4)0.f;
      }
      __syncthreads();  // drains the just-issued stage + protects Bs[b] for overwrite
    }
  }

  // merge the 16 l15-lanes sharing each row; rows wave-exclusive -> one slot per split
#pragma unroll
  for (int rr = 0; rr < 4; rr++){
    float mv = sm[rr], sv2 = ssum[rr];
#pragma unroll
    for (int mask = 1; mask < 16; mask <<= 1){
      float m2 = __shfl_xor(mv, mask);
      float s2 = __shfl_xor(sv2, mask);
      float M = fmaxf(mv, m2);
      sv2 = sv2 * ex2(mv - M) + s2 * ex2(m2 - M);
      mv = M;
    }
    if (l15 == 0){
      int rl = w * 16 + quad * 4 + rr;
      int o = split * B_N + i0 + rl;
      wsM[o] = mv; wsS[o] = sv2;
    }
  }
}

// ---------------- node 4. finale: 32 blocks, log2-domain merge, atomic finish ----------------
__global__ __launch_bounds__(256)
void finale_kernel(const float* __restrict__ wsM, const float* __restrict__ wsS,
                   const float* __restrict__ numer, const int* __restrict__ jsel,
                   float* __restrict__ acc4, float* __restrict__ out)
{
  const int tid = threadIdx.x;
  const int row = blockIdx.x * 256 + tid;   // 32*256 = 8192, one row per thread
  float M = -3.0e38f, S = 0.f;
#pragma unroll
  for (int p = 0; p < NPART; p++){
    float m2 = wsM[p * B_N + row], s2 = wsS[p * B_N + row];
    float Mn = fmaxf(M, m2);
    S = S * ex2(M - Mn) + s2 * ex2(m2 - Mn);
    M = Mn;
  }
  bool v = (jsel[row] >= 0) && (M > -5e29f);
  float s = v ? (LN2F * (M + lg2(S) - numer[row])) : 0.f;
  unsigned n = v ? 1u : 0u;
#pragma unroll
  for (int off = 32; off > 0; off >>= 1){ s += __shfl_down(s, off); n += __shfl_down(n, off); }
  __shared__ float ssm[4]; __shared__ unsigned snm[4];
  if ((tid & 63) == 0){ ssm[tid >> 6] = s; snm[tid >> 6] = n; }
  __syncthreads();
  if (tid == 0){
    float bs = ssm[0] + ssm[1] + ssm[2] + ssm[3];
    unsigned bn = snm[0] + snm[1] + snm[2] + snm[3];
    atomicAdd(&acc4[0], bs);
    atomicAdd((unsigned*)&acc4[1], bn);
    __threadfence();
    unsigned old = atomicAdd((unsigned*)&acc4[2], 1u);
    if (old == 31u){  // last block: publish
      float St = atomicAdd(&acc4[0], 0.f);
      unsigned Nt = atomicAdd((unsigned*)&acc4[1], 0u);
      out[0] = (Nt > 0u) ? (St / (float)Nt) : 0.f;
    }
  }
}

extern "C" void kernel_launch(void* const* d_in, const int* in_sizes, int n_in,
                              void* d_out, int out_size, void* d_ws, size_t ws_size,
                              hipStream_t stream)
{
  const float* E      = (const float*)d_in[0];
  const int*   labels = (const int*)d_in[1];
  float*       out    = (float*)d_out;

  ushort_t* Ebf = (ushort_t*)d_ws;                     // 4 MB
  float* wsM    = (float*)(Ebf + (size_t)B_N * D_K);   // 512 KB (16 partials)
  float* wsS    = wsM + NPART * B_N;                   // 512 KB
  float* sqb    = wsS + NPART * B_N;                   // 32 KB
  float* numer  = sqb + B_N;                           // 32 KB
  int* jsel     = (int*)(numer + B_N);                 // 32 KB
  float* acc4   = (float*)(jsel + B_N);                // 16 B accumulators
  int* cls_cnt  = (int*)(acc4 + 4);                    // 400 B
  int* clist    = cls_cnt + NCLS;                      // 200 KB

  prep_kernel<<<B_N / 4 + NCLS, 256, 0, stream>>>(E, Ebf, sqb, acc4, labels, cls_cnt, clist);
  rowsel_kernel<<<B_N / 4, 256, 0, stream>>>(labels, cls_cnt, clist, jsel);
  fused_kernel<<<(B_N / BI) * NSPLIT, 256, 0, stream>>>(Ebf, labels, sqb, jsel, numer, wsM, wsS);
  finale_kernel<<<B_N / 256, 256, 0, stream>>>(wsM, wsS, numer, jsel, acc4, out);
}